// Round 10
// baseline (150.359 us; speedup 1.0000x reference)
//
#include <hip/hip_runtime.h>
#include <hip/hip_bf16.h>

#define NN 50000
#define NE 800000
#define DIM 128
#define NTILES (NN / 16)
#define GEMM_BLOCKS 784

#define XF8_BLOCKS 3125  // 800000 threads x 8 elems = 6.4M
#define OFF_BLOCKS 196   // covers NN+1 = 50001
#define V_BLOCKS 128     // 32768 V elements

typedef float f32x4 __attribute__((ext_vector_type(4)));
typedef float f32x2 __attribute__((ext_vector_type(2)));
typedef int   i32x2 __attribute__((ext_vector_type(2)));
typedef __bf16 bf16x8 __attribute__((ext_vector_type(8)));

static __device__ __forceinline__ unsigned short bfbits(float f) {
    __bf16 b = (__bf16)f; return __builtin_bit_cast(unsigned short, b);
}

// prep: [0,XF8) x->fp8(e4m3) | [XF8,+OFF) lower_bound offsets | [+V) build V
__global__ void __launch_bounds__(256) prep(const float* __restrict__ x,
        const float* __restrict__ Wg, const float* __restrict__ Wl,
        const int* __restrict__ seg,
        unsigned char* __restrict__ xf8, int* __restrict__ off,
        __bf16* __restrict__ V) {
    int b = blockIdx.x;
    int t = threadIdx.x;
    if (b < XF8_BLOCKS) {
        int i = b * 256 + t;                 // < 800000
        const float* p = x + (size_t)i * 8;
        f32x4 v0 = *reinterpret_cast<const f32x4*>(p);
        f32x4 v1 = *reinterpret_cast<const f32x4*>(p + 4);
        int lo = __builtin_amdgcn_cvt_pk_fp8_f32(v0[0], v0[1], 0, false);
        lo     = __builtin_amdgcn_cvt_pk_fp8_f32(v0[2], v0[3], lo, true);
        int hi = __builtin_amdgcn_cvt_pk_fp8_f32(v1[0], v1[1], 0, false);
        hi     = __builtin_amdgcn_cvt_pk_fp8_f32(v1[2], v1[3], hi, true);
        i32x2 o = {lo, hi};
        *reinterpret_cast<i32x2*>(xf8 + (size_t)i * 8) = o;
    } else if (b < XF8_BLOCKS + OFF_BLOCKS) {
        int n = (b - XF8_BLOCKS) * 256 + t;
        if (n <= NN) {
            int lo = 0, hi = NE;
            while (lo < hi) {
                int mid = (lo + hi) >> 1;
                if (seg[mid] < n) lo = mid + 1; else hi = mid;
            }
            off[n] = lo;
        }
    } else {
        int i = (b - XF8_BLOCKS - OFF_BLOCKS) * 256 + t;   // < 32768
        int d = i >> 8;
        int k = i & 255;
        float v;
        if (k < DIM) v = Wg[d * DIM + k];
        else         v = Wg[d * DIM + (k - DIM)] + Wl[d * DIM + (k - DIM)];
        V[i] = (__bf16)v;
    }
}

// seg_mean: one wave per node; lane holds dims 2l,2l+1 as fp8 pair (ushort);
// 8 gathers (128B rows) in flight; mean in fp32 -> bf16 pair.
__global__ void __launch_bounds__(256) seg_mean(const unsigned char* __restrict__ xf8,
        const int* __restrict__ nidx, const int* __restrict__ off,
        int* __restrict__ cnt_ws, __bf16* __restrict__ meanb) {
    int n = blockIdx.x * 4 + (threadIdx.x >> 6);
    if (n >= NN) return;
    int lane = threadIdx.x & 63;
    int s = off[n], e = off[n + 1];
    const unsigned short* xu = reinterpret_cast<const unsigned short*>(xf8);
    float a0 = 0.f, a1 = 0.f, b0 = 0.f, b1 = 0.f;
    int i = s;
    for (; i + 8 <= e; i += 8) {
        unsigned short u0 = xu[nidx[i]   * 64 + lane];
        unsigned short u1 = xu[nidx[i+1] * 64 + lane];
        unsigned short u2 = xu[nidx[i+2] * 64 + lane];
        unsigned short u3 = xu[nidx[i+3] * 64 + lane];
        unsigned short u4 = xu[nidx[i+4] * 64 + lane];
        unsigned short u5 = xu[nidx[i+5] * 64 + lane];
        unsigned short u6 = xu[nidx[i+6] * 64 + lane];
        unsigned short u7 = xu[nidx[i+7] * 64 + lane];
        f32x2 f0 = __builtin_amdgcn_cvt_pk_f32_fp8((int)u0, false);
        f32x2 f1 = __builtin_amdgcn_cvt_pk_f32_fp8((int)u1, false);
        f32x2 f2 = __builtin_amdgcn_cvt_pk_f32_fp8((int)u2, false);
        f32x2 f3 = __builtin_amdgcn_cvt_pk_f32_fp8((int)u3, false);
        f32x2 f4 = __builtin_amdgcn_cvt_pk_f32_fp8((int)u4, false);
        f32x2 f5 = __builtin_amdgcn_cvt_pk_f32_fp8((int)u5, false);
        f32x2 f6 = __builtin_amdgcn_cvt_pk_f32_fp8((int)u6, false);
        f32x2 f7 = __builtin_amdgcn_cvt_pk_f32_fp8((int)u7, false);
        a0 += f0[0] + f2[0]; a1 += f0[1] + f2[1];
        b0 += f1[0] + f3[0]; b1 += f1[1] + f3[1];
        a0 += f4[0] + f6[0]; a1 += f4[1] + f6[1];
        b0 += f5[0] + f7[0]; b1 += f5[1] + f7[1];
    }
    for (; i + 4 <= e; i += 4) {
        unsigned short u0 = xu[nidx[i]   * 64 + lane];
        unsigned short u1 = xu[nidx[i+1] * 64 + lane];
        unsigned short u2 = xu[nidx[i+2] * 64 + lane];
        unsigned short u3 = xu[nidx[i+3] * 64 + lane];
        f32x2 f0 = __builtin_amdgcn_cvt_pk_f32_fp8((int)u0, false);
        f32x2 f1 = __builtin_amdgcn_cvt_pk_f32_fp8((int)u1, false);
        f32x2 f2 = __builtin_amdgcn_cvt_pk_f32_fp8((int)u2, false);
        f32x2 f3 = __builtin_amdgcn_cvt_pk_f32_fp8((int)u3, false);
        a0 += f0[0] + f2[0]; a1 += f0[1] + f2[1];
        b0 += f1[0] + f3[0]; b1 += f1[1] + f3[1];
    }
    for (; i < e; ++i) {
        unsigned short u = xu[nidx[i] * 64 + lane];
        f32x2 f = __builtin_amdgcn_cvt_pk_f32_fp8((int)u, false);
        a0 += f[0]; a1 += f[1];
    }
    float s0 = a0 + b0, s1 = a1 + b1;
    int c = e - s;
    float inv = c > 0 ? 1.f / (float)c : 0.f;
    unsigned o = (unsigned)bfbits(s0 * inv) | ((unsigned)bfbits(s1 * inv) << 16);
    reinterpret_cast<unsigned*>(meanb)[n * 64 + lane] = o;
    if (lane == 0) cnt_ws[n] = c;
}

// gemm_ep: 4 waves/block; wave w owns output dims [w*32, w*32+32) with B
// register-resident; grid-strides over 16-row tiles. K=256:
// self part from x (fp32 -> bf16 in-register), mean part from meanb.
__global__ void __launch_bounds__(256) gemm_ep(const float* __restrict__ x,
        const __bf16* __restrict__ meanb, const __bf16* __restrict__ V,
        const float* __restrict__ bias, const int* __restrict__ cnt_ws,
        float* __restrict__ out) {
    int tid = threadIdx.x;
    int w = tid >> 6;
    int lane = tid & 63;
    int rowin = lane & 15;
    int kg = lane >> 4;
    int rbase = kg * 4;

    bf16x8 Bf[8][2];
    #pragma unroll
    for (int s = 0; s < 8; ++s)
        #pragma unroll
        for (int ff = 0; ff < 2; ++ff) {
            int d = (w * 2 + ff) * 16 + rowin;
            Bf[s][ff] = *reinterpret_cast<const bf16x8*>(&V[d * 256 + s * 32 + kg * 8]);
        }
    float bs0 = bias[(w * 2) * 16 + rowin];
    float bs1 = bias[(w * 2 + 1) * 16 + rowin];

    for (int t = blockIdx.x; t < NTILES; t += gridDim.x) {
        int m0 = t * 16;
        int row = m0 + rowin;
        f32x4 acc0 = {}, acc1 = {};
        #pragma unroll
        for (int s = 0; s < 4; ++s) {
            const float* xp = x + (size_t)row * DIM + s * 32 + kg * 8;
            f32x4 v0 = *reinterpret_cast<const f32x4*>(xp);
            f32x4 v1 = *reinterpret_cast<const f32x4*>(xp + 4);
            bf16x8 a;
            a[0]=(__bf16)v0[0]; a[1]=(__bf16)v0[1]; a[2]=(__bf16)v0[2]; a[3]=(__bf16)v0[3];
            a[4]=(__bf16)v1[0]; a[5]=(__bf16)v1[1]; a[6]=(__bf16)v1[2]; a[7]=(__bf16)v1[3];
            acc0 = __builtin_amdgcn_mfma_f32_16x16x32_bf16(a, Bf[s][0], acc0, 0, 0, 0);
            acc1 = __builtin_amdgcn_mfma_f32_16x16x32_bf16(a, Bf[s][1], acc1, 0, 0, 0);
        }
        #pragma unroll
        for (int s = 0; s < 4; ++s) {
            bf16x8 a = *reinterpret_cast<const bf16x8*>(&meanb[row * DIM + s * 32 + kg * 8]);
            acc0 = __builtin_amdgcn_mfma_f32_16x16x32_bf16(a, Bf[s + 4][0], acc0, 0, 0, 0);
            acc1 = __builtin_amdgcn_mfma_f32_16x16x32_bf16(a, Bf[s + 4][1], acc1, 0, 0, 0);
        }
        // epilogue: C/D col = lane&15, row = (lane>>4)*4 + r  (verified r2/r4/r9)
        #pragma unroll
        for (int r = 0; r < 4; ++r) {
            int n = m0 + rbase + r;
            int c = cnt_ws[n];
            float v0 = acc0[r];
            float z0 = v0 + (c == 0 ? v0 : 0.f) + bs0;
            out[n * DIM + (w * 2) * 16 + rowin] = z0 > 0.f ? z0 : expm1f(z0);
            float v1 = acc1[r];
            float z1 = v1 + (c == 0 ? v1 : 0.f) + bs1;
            out[n * DIM + (w * 2 + 1) * 16 + rowin] = z1 > 0.f ? z1 : expm1f(z1);
        }
    }
}

extern "C" void kernel_launch(void* const* d_in, const int* in_sizes, int n_in,
                              void* d_out, int out_size, void* d_ws, size_t ws_size,
                              hipStream_t stream) {
    const float* x    = (const float*)d_in[0];
    const float* Wg   = (const float*)d_in[1];
    const float* Wl   = (const float*)d_in[2];
    const float* bias = (const float*)d_in[3];
    const int*   nidx = (const int*)d_in[4];
    const int*   seg  = (const int*)d_in[5];
    float* out = (float*)d_out;

    char* p = (char*)d_ws;
    __bf16* V = (__bf16*)p;           p += DIM * 256 * 2;                      // 64 KB
    int* off = (int*)p;               p += (((NN + 1) * 4) + 511) & ~511ull;
    int* cnt = (int*)p;               p += ((NN * 4) + 511) & ~511ull;
    __bf16* meanb = (__bf16*)p;       p += (size_t)NN * DIM * 2;               // 12.8 MB
    unsigned char* xf8 = (unsigned char*)p;                                    // 6.4 MB

    prep     <<<XF8_BLOCKS + OFF_BLOCKS + V_BLOCKS, 256, 0, stream>>>(x, Wg, Wl, seg, xf8, off, V);
    seg_mean <<<(NN + 3) / 4, 256, 0, stream>>>(xf8, nidx, off, cnt, meanb);
    gemm_ep  <<<GEMM_BLOCKS, 256, 0, stream>>>(x, meanb, V, bias, cnt, out);
}